// Round 4
// baseline (641.691 us; speedup 1.0000x reference)
//
#include <hip/hip_runtime.h>

#define EPS 1e-4f

constexpr int Bn = 64;
constexpr int Nn = 1024;
constexpr int Mn = 1024;
constexpr int NSPLIT = 16;           // fuse0/rowcol row chunks -> 64 rows/block
constexpr int CHUNK  = Nn / NSPLIT;  // 64
constexpr int SLOT   = 16;           // partial col-sum slots per sample (1/block)

typedef float f32x4 __attribute__((ext_vector_type(4)));

// ---- fp16 helpers via clang builtin _Float16 (no header dependency).
__device__ __forceinline__ unsigned pkh2(float a, float b) {
    union { _Float16 h; unsigned short u; } ta, tb;
    ta.h = (_Float16)a; tb.h = (_Float16)b;
    return (unsigned)ta.u | ((unsigned)tb.u << 16);
}
__device__ __forceinline__ float lo16(unsigned v) {
    union { unsigned short u; _Float16 h; } t; t.u = (unsigned short)(v & 0xffffu);
    return (float)t.h;
}
__device__ __forceinline__ float hi16(unsigned v) {
    union { unsigned short u; _Float16 h; } t; t.u = (unsigned short)(v >> 16);
    return (float)t.h;
}

// ---- 64-lane wave sum via DPP (6 VALU adds, no DS ops, no LDS).
// row_shr:1/2/4/8 builds 16-lane row sums; row_bcast:15/31 folds rows;
// lane 63 holds the total -> readlane broadcast (wave-uniform SGPR).
template<int CTRL>
__device__ __forceinline__ float dpp_add(float x) {
    int t = __builtin_amdgcn_update_dpp(0, __float_as_int(x), CTRL, 0xf, 0xf, true);
    return x + __int_as_float(t);
}
__device__ __forceinline__ float wave_sum64(float x) {
    x = dpp_add<0x111>(x);   // row_shr:1
    x = dpp_add<0x112>(x);   // row_shr:2
    x = dpp_add<0x114>(x);   // row_shr:4
    x = dpp_add<0x118>(x);   // row_shr:8
    x = dpp_add<0x142>(x);   // row_bcast:15
    x = dpp_add<0x143>(x);   // row_bcast:31
    return __int_as_float(__builtin_amdgcn_readlane(__float_as_int(x), 63));
}

// ---- shared: reduce SLOT partial col-sum slots from pin -> masked reciprocal
// c[1024] in LDS. Thread t owns cols 4t..4t+3.
__device__ __forceinline__ void fold_c(const float* __restrict__ pin,
                                       const int* __restrict__ ncols,
                                       int b, int t, float* cs) {
    const int m0 = t * 4;
    f32x4 s4 = {0.f, 0.f, 0.f, 0.f};
    #pragma unroll
    for (int k = 0; k < SLOT; ++k)
        s4 += *reinterpret_cast<const f32x4*>(pin + ((size_t)(b * SLOT + k)) * Mn + m0);
    const int nc = ncols[b];
    f32x4 r;
    r.x = (m0 + 0 < nc && s4.x > 0.f) ? 1.f / s4.x : 0.f;
    r.y = (m0 + 1 < nc && s4.y > 0.f) ? 1.f / s4.y : 0.f;
    r.z = (m0 + 2 < nc && s4.z > 0.f) ? 1.f / s4.z : 0.f;
    r.w = (m0 + 3 < nc && s4.w > 0.f) ? 1.f / s4.w : 0.f;
    *reinterpret_cast<f32x4*>(&cs[m0]) = r;
}

// ---- pass 0 fused: compress s+eps -> fp16 sc AND accumulate unmasked col sums.
// Plain (cached) loads: NT hint removed -- unverified BW effect, plain is the
// measured-6.3TB/s path. Depth-1 register prefetch retained.
__global__ __launch_bounds__(256) void fuse0_kernel(
        const float* __restrict__ s, unsigned short* __restrict__ sc,
        float* __restrict__ p) {
    __shared__ float4 red[256];      // 4 KB: half-1 partials
    const int b = blockIdx.x, sp = blockIdx.y;
    const int t = threadIdx.x, half = t >> 7, tc = t & 127;
    float acc[8];
    #pragma unroll
    for (int k = 0; k < 8; ++k) acc[k] = 0.f;
    const size_t roff0 = ((size_t)b * Nn + sp * CHUNK + half) * Mn;
    const f32x4* src0 = reinterpret_cast<const f32x4*>(s + roff0) + 2 * tc;
    f32x4 v0 = src0[0];
    f32x4 v1 = src0[1];
    for (int j = 0; j < CHUNK; j += 2) {
        f32x4 n0 = {}, n1 = {};
        if (j < CHUNK - 2) {
            const f32x4* nsrc = src0 + (size_t)(j + 2) * (Mn / 4);
            n0 = nsrc[0];
            n1 = nsrc[1];
        }
        f32x4 w0 = v0 + EPS, w1 = v1 + EPS;
        acc[0] += w0.x; acc[1] += w0.y; acc[2] += w0.z; acc[3] += w0.w;
        acc[4] += w1.x; acc[5] += w1.y; acc[6] += w1.z; acc[7] += w1.w;
        uint4 wpk = { pkh2(w0.x, w0.y), pkh2(w0.z, w0.w),
                      pkh2(w1.x, w1.y), pkh2(w1.z, w1.w) };
        const size_t roff = roff0 + (size_t)j * Mn;
        reinterpret_cast<uint4*>(sc + roff)[tc] = wpk;
        v0 = n0; v1 = n1;
    }
    if (half) {
        red[tc * 2]     = make_float4(acc[0], acc[1], acc[2], acc[3]);
        red[tc * 2 + 1] = make_float4(acc[4], acc[5], acc[6], acc[7]);
    }
    __syncthreads();
    if (!half) {
        const float4 r0 = red[tc * 2], r1 = red[tc * 2 + 1];
        float* pp = p + ((size_t)(b * SLOT + sp)) * Mn + tc * 8;
        float4 o0 = {acc[0] + r0.x, acc[1] + r0.y, acc[2] + r0.z, acc[3] + r0.w};
        float4 o1 = {acc[4] + r1.x, acc[5] + r1.y, acc[6] + r1.z, acc[7] + r1.w};
        *reinterpret_cast<float4*>(pp)     = o0;
        *reinterpret_cast<float4*>(pp + 4) = o1;
    }
}

// ---- FUSED (col-finalize + row-pass + col-pass) over fp16 sc, one sweep.
// Row sums now via DPP wave_sum64 (6 VALU adds) instead of 6-deep ds-op
// butterfly chains: kills the serialized DS latency per row pair.
__global__ __launch_bounds__(256) void rowcol_kernel(
        const unsigned short* __restrict__ sc, const float* __restrict__ pin,
        const int* __restrict__ nrows, const int* __restrict__ ncols,
        float* __restrict__ pout) {
    __shared__ float cs[1024];       // 4 KB: column reciprocals
    __shared__ float4 red[4][256];   // 16 KB
    const int b = blockIdx.x;
    const int t = threadIdx.x, w = t >> 6, l = t & 63;
    fold_c(pin, ncols, b, t, cs);
    __syncthreads();
    const f32x4 c0 = *reinterpret_cast<const f32x4*>(&cs[8 * l]);
    const f32x4 c1 = *reinterpret_cast<const f32x4*>(&cs[8 * l + 4]);
    const f32x4 c2 = *reinterpret_cast<const f32x4*>(&cs[512 + 8 * l]);
    const f32x4 c3 = *reinterpret_cast<const f32x4*>(&cs[512 + 8 * l + 4]);
    const int n0 = blockIdx.y * 64 + w * 16;
    const int nr = nrows[b];
    float acc[16];
    #pragma unroll
    for (int k = 0; k < 16; ++k) acc[k] = 0.f;
    const uint4* base = reinterpret_cast<const uint4*>(sc + ((size_t)b * Nn + n0) * Mn);
    uint4 a0 = base[l], d0 = base[64 + l], a1 = base[128 + l], d1 = base[192 + l];
    for (int j = 0; j < 16; j += 2) {
        uint4 na0 = {}, nd0 = {}, na1 = {}, nd1 = {};
        if (j < 14) {
            const uint4* nx = base + (size_t)(j + 2) * 128;
            na0 = nx[l]; nd0 = nx[64 + l]; na1 = nx[128 + l]; nd1 = nx[192 + l];
        }
        const float x0 = lo16(a0.x),  x1 = hi16(a0.x),  x2 = lo16(a0.y),  x3 = hi16(a0.y);
        const float x4 = lo16(a0.z),  x5 = hi16(a0.z),  x6 = lo16(a0.w),  x7 = hi16(a0.w);
        const float x8 = lo16(d0.x),  x9 = hi16(d0.x),  x10 = lo16(d0.y), x11 = hi16(d0.y);
        const float x12 = lo16(d0.z), x13 = hi16(d0.z), x14 = lo16(d0.w), x15 = hi16(d0.w);
        const float y0 = lo16(a1.x),  y1 = hi16(a1.x),  y2 = lo16(a1.y),  y3 = hi16(a1.y);
        const float y4 = lo16(a1.z),  y5 = hi16(a1.z),  y6 = lo16(a1.w),  y7 = hi16(a1.w);
        const float y8 = lo16(d1.x),  y9 = hi16(d1.x),  y10 = lo16(d1.y), y11 = hi16(d1.y);
        const float y12 = lo16(d1.z), y13 = hi16(d1.z), y14 = lo16(d1.w), y15 = hi16(d1.w);
        float part0 = x0 * c0.x + x1 * c0.y + x2 * c0.z + x3 * c0.w
                    + x4 * c1.x + x5 * c1.y + x6 * c1.z + x7 * c1.w
                    + x8 * c2.x + x9 * c2.y + x10 * c2.z + x11 * c2.w
                    + x12 * c3.x + x13 * c3.y + x14 * c3.z + x15 * c3.w;
        float part1 = y0 * c0.x + y1 * c0.y + y2 * c0.z + y3 * c0.w
                    + y4 * c1.x + y5 * c1.y + y6 * c1.z + y7 * c1.w
                    + y8 * c2.x + y9 * c2.y + y10 * c2.z + y11 * c2.w
                    + y12 * c3.x + y13 * c3.y + y14 * c3.z + y15 * c3.w;
        part0 = wave_sum64(part0);
        part1 = wave_sum64(part1);
        const int n = n0 + j;
        const float rv0 = (n < nr && part0 > 0.f) ? 1.f / part0 : 0.f;
        const float rv1 = (n + 1 < nr && part1 > 0.f) ? 1.f / part1 : 0.f;
        acc[0]  += x0 * rv0 + y0 * rv1;   acc[1]  += x1 * rv0 + y1 * rv1;
        acc[2]  += x2 * rv0 + y2 * rv1;   acc[3]  += x3 * rv0 + y3 * rv1;
        acc[4]  += x4 * rv0 + y4 * rv1;   acc[5]  += x5 * rv0 + y5 * rv1;
        acc[6]  += x6 * rv0 + y6 * rv1;   acc[7]  += x7 * rv0 + y7 * rv1;
        acc[8]  += x8 * rv0 + y8 * rv1;   acc[9]  += x9 * rv0 + y9 * rv1;
        acc[10] += x10 * rv0 + y10 * rv1; acc[11] += x11 * rv0 + y11 * rv1;
        acc[12] += x12 * rv0 + y12 * rv1; acc[13] += x13 * rv0 + y13 * rv1;
        acc[14] += x14 * rv0 + y14 * rv1; acc[15] += x15 * rv0 + y15 * rv1;
        a0 = na0; d0 = nd0; a1 = na1; d1 = nd1;
    }
    red[w][2 * l]       = make_float4(acc[0], acc[1], acc[2], acc[3]);
    red[w][2 * l + 1]   = make_float4(acc[4], acc[5], acc[6], acc[7]);
    red[w][128 + 2 * l] = make_float4(acc[8], acc[9], acc[10], acc[11]);
    red[w][129 + 2 * l] = make_float4(acc[12], acc[13], acc[14], acc[15]);
    __syncthreads();
    const float4 r0 = red[0][t], r1 = red[1][t], r2 = red[2][t], r3 = red[3][t];
    float4 o = { r0.x + r1.x + r2.x + r3.x, r0.y + r1.y + r2.y + r3.y,
                 r0.z + r1.z + r2.z + r3.z, r0.w + r1.w + r2.w + r3.w };
    float* pp = pout + ((size_t)(b * SLOT) + blockIdx.y) * Mn;
    reinterpret_cast<float4*>(pp)[t] = o;
}

// ---- final pass: fold c, then f32 s read, DPP row factor, output write.
// Plain loads (NT removed); NT kept on out stores only (write-once stream).
__global__ __launch_bounds__(256) void final_kernel(
        const float* __restrict__ s, const float* __restrict__ pin,
        const int* __restrict__ nrows, const int* __restrict__ ncols,
        float* __restrict__ out) {
    __shared__ float cs[1024];       // 4 KB
    const int b = blockIdx.x;
    const int t = threadIdx.x, w = t >> 6, l = t & 63;
    fold_c(pin, ncols, b, t, cs);
    __syncthreads();
    f32x4 cc[4];
    #pragma unroll
    for (int k = 0; k < 4; ++k)
        cc[k] = *reinterpret_cast<const f32x4*>(&cs[256 * k + 4 * l]);
    const int n0 = blockIdx.y * 32 + w * 8;
    const int nr = nrows[b];
    const size_t roff0 = ((size_t)b * Nn + n0) * Mn;
    const f32x4* row0 = reinterpret_cast<const f32x4*>(s + roff0);
    f32x4 a[4];
    #pragma unroll
    for (int k = 0; k < 4; ++k)
        a[k] = row0[64 * k + l];
    for (int j = 0; j < 8; ++j) {
        f32x4 na[4] = {};
        if (j < 7) {
            const f32x4* nrow = row0 + (size_t)(j + 1) * (Mn / 4);
            #pragma unroll
            for (int k = 0; k < 4; ++k)
                na[k] = nrow[64 * k + l];
        }
        float part = 0.f;
        #pragma unroll
        for (int k = 0; k < 4; ++k) {
            a[k] += EPS;
            part += a[k].x * cc[k].x + a[k].y * cc[k].y
                  + a[k].z * cc[k].z + a[k].w * cc[k].w;
        }
        part = wave_sum64(part);
        const int n = n0 + j;
        const float rv = (n < nr && part > 0.f) ? 1.f / part : 0.f;
        f32x4* orow = reinterpret_cast<f32x4*>(out + roff0 + (size_t)j * Mn);
        #pragma unroll
        for (int k = 0; k < 4; ++k) {
            f32x4 o;
            o.x = a[k].x * cc[k].x * rv;
            o.y = a[k].y * cc[k].y * rv;
            o.z = a[k].z * cc[k].z * rv;
            o.w = a[k].w * cc[k].w * rv;
            __builtin_nontemporal_store(o, orow + 64 * k + l);
        }
        #pragma unroll
        for (int k = 0; k < 4; ++k) a[k] = na[k];
    }
}

extern "C" void kernel_launch(void* const* d_in, const int* in_sizes, int n_in,
                              void* d_out, int out_size, void* d_ws, size_t ws_size,
                              hipStream_t stream) {
    const float* s     = (const float*)d_in[0];
    const int*   nrows = (const int*)d_in[1];
    const int*   ncols = (const int*)d_in[2];
    float* out = (float*)d_out;

    // workspace: sc fp16 [B*N*M] (128 MiB) | pA [B*16*M] (4 MB) | pB (4 MB)
    unsigned short* sc = (unsigned short*)d_ws;
    float* pA = (float*)(sc + (size_t)Bn * Nn * Mn);
    float* pB = pA + (size_t)Bn * SLOT * Mn;

    // i=0: col-sum pass fused with fp16 compression (unmasked, r==1)
    fuse0_kernel<<<dim3(Bn, NSPLIT), 256, 0, stream>>>(s, sc, pA);
    // i=1..8: four fused (c-finalize + row-norm + col-sum) sweeps, ping-pong p
    rowcol_kernel<<<dim3(Bn, NSPLIT), 256, 0, stream>>>(sc, pA, nrows, ncols, pB);
    rowcol_kernel<<<dim3(Bn, NSPLIT), 256, 0, stream>>>(sc, pB, nrows, ncols, pA);
    rowcol_kernel<<<dim3(Bn, NSPLIT), 256, 0, stream>>>(sc, pA, nrows, ncols, pB);
    rowcol_kernel<<<dim3(Bn, NSPLIT), 256, 0, stream>>>(sc, pB, nrows, ncols, pA);
    // i=9: c-finalize + final row normalization fused with output write (f32)
    final_kernel<<<dim3(Bn, Nn / 32), 256, 0, stream>>>(s, pA, nrows, ncols, out);
}

// Round 5
// 640.095 us; speedup vs baseline: 1.0025x; 1.0025x over previous
//
#include <hip/hip_runtime.h>

#define EPS 1e-4f

constexpr int Bn = 64;
constexpr int Nn = 1024;
constexpr int Mn = 1024;
constexpr int NSPLIT = 16;           // row chunks -> 64 rows/block
constexpr int CHUNK  = Nn / NSPLIT;  // 64
constexpr int SLOT   = 16;           // partial col-sum slots per sample (1/block)

typedef float f32x4 __attribute__((ext_vector_type(4)));

// ---- fp16 helpers via clang builtin _Float16 (no header dependency).
__device__ __forceinline__ unsigned pkh2(float a, float b) {
    union { _Float16 h; unsigned short u; } ta, tb;
    ta.h = (_Float16)a; tb.h = (_Float16)b;
    return (unsigned)ta.u | ((unsigned)tb.u << 16);
}
__device__ __forceinline__ float lo16(unsigned v) {
    union { unsigned short u; _Float16 h; } t; t.u = (unsigned short)(v & 0xffffu);
    return (float)t.h;
}
__device__ __forceinline__ float hi16(unsigned v) {
    union { unsigned short u; _Float16 h; } t; t.u = (unsigned short)(v >> 16);
    return (float)t.h;
}

// ---- shared: reduce SLOT partial col-sum slots from pin -> masked reciprocal
// c[1024] in LDS. Thread t owns cols 4t..4t+3.
__device__ __forceinline__ void fold_c(const float* __restrict__ pin,
                                       const int* __restrict__ ncols,
                                       int b, int t, float* cs) {
    const int m0 = t * 4;
    f32x4 s4 = {0.f, 0.f, 0.f, 0.f};
    #pragma unroll
    for (int k = 0; k < SLOT; ++k)
        s4 += *reinterpret_cast<const f32x4*>(pin + ((size_t)(b * SLOT + k)) * Mn + m0);
    const int nc = ncols[b];
    f32x4 r;
    r.x = (m0 + 0 < nc && s4.x > 0.f) ? 1.f / s4.x : 0.f;
    r.y = (m0 + 1 < nc && s4.y > 0.f) ? 1.f / s4.y : 0.f;
    r.z = (m0 + 2 < nc && s4.z > 0.f) ? 1.f / s4.z : 0.f;
    r.w = (m0 + 3 < nc && s4.w > 0.f) ? 1.f / s4.w : 0.f;
    *reinterpret_cast<f32x4*>(&cs[m0]) = r;
}

// ---- pass 0 fused: compress s+eps -> fp16 sc AND accumulate unmasked col sums.
// NT loads of s (one-shot stream; keep sc L3-resident); plain sc stores.
__global__ __launch_bounds__(256) void fuse0_kernel(
        const float* __restrict__ s, unsigned short* __restrict__ sc,
        float* __restrict__ p) {
    __shared__ float4 red[256];      // 4 KB: half-1 partials
    const int b = blockIdx.x, sp = blockIdx.y;
    const int t = threadIdx.x, half = t >> 7, tc = t & 127;
    float acc[8];
    #pragma unroll
    for (int k = 0; k < 8; ++k) acc[k] = 0.f;
    const size_t roff0 = ((size_t)b * Nn + sp * CHUNK + half) * Mn;
    const f32x4* src0 = reinterpret_cast<const f32x4*>(s + roff0) + 2 * tc;
    f32x4 v0 = __builtin_nontemporal_load(src0);
    f32x4 v1 = __builtin_nontemporal_load(src0 + 1);
    for (int j = 0; j < CHUNK; j += 2) {
        f32x4 n0 = {}, n1 = {};
        if (j < CHUNK - 2) {
            const f32x4* nsrc = src0 + (size_t)(j + 2) * (Mn / 4);
            n0 = __builtin_nontemporal_load(nsrc);
            n1 = __builtin_nontemporal_load(nsrc + 1);
        }
        f32x4 w0 = v0 + EPS, w1 = v1 + EPS;
        acc[0] += w0.x; acc[1] += w0.y; acc[2] += w0.z; acc[3] += w0.w;
        acc[4] += w1.x; acc[5] += w1.y; acc[6] += w1.z; acc[7] += w1.w;
        uint4 wpk = { pkh2(w0.x, w0.y), pkh2(w0.z, w0.w),
                      pkh2(w1.x, w1.y), pkh2(w1.z, w1.w) };
        const size_t roff = roff0 + (size_t)j * Mn;
        reinterpret_cast<uint4*>(sc + roff)[tc] = wpk;
        v0 = n0; v1 = n1;
    }
    if (half) {
        red[tc * 2]     = make_float4(acc[0], acc[1], acc[2], acc[3]);
        red[tc * 2 + 1] = make_float4(acc[4], acc[5], acc[6], acc[7]);
    }
    __syncthreads();
    if (!half) {
        const float4 r0 = red[tc * 2], r1 = red[tc * 2 + 1];
        float* pp = p + ((size_t)(b * SLOT + sp)) * Mn + tc * 8;
        float4 o0 = {acc[0] + r0.x, acc[1] + r0.y, acc[2] + r0.z, acc[3] + r0.w};
        float4 o1 = {acc[4] + r1.x, acc[5] + r1.y, acc[6] + r1.z, acc[7] + r1.w};
        *reinterpret_cast<float4*>(pp)     = o0;
        *reinterpret_cast<float4*>(pp + 4) = o1;
    }
}

// ---- FUSED (col-finalize + row-pass + col-pass) over fp16 sc, one sweep.
// 2 rows/step, depth-1 register prefetch, shfl_xor butterflies (best-measured).
__global__ __launch_bounds__(256) void rowcol_kernel(
        const unsigned short* __restrict__ sc, const float* __restrict__ pin,
        const int* __restrict__ nrows, const int* __restrict__ ncols,
        float* __restrict__ pout) {
    __shared__ float cs[1024];       // 4 KB: column reciprocals
    __shared__ float4 red[4][256];   // 16 KB
    const int b = blockIdx.x;
    const int t = threadIdx.x, w = t >> 6, l = t & 63;
    fold_c(pin, ncols, b, t, cs);
    __syncthreads();
    const f32x4 c0 = *reinterpret_cast<const f32x4*>(&cs[8 * l]);
    const f32x4 c1 = *reinterpret_cast<const f32x4*>(&cs[8 * l + 4]);
    const f32x4 c2 = *reinterpret_cast<const f32x4*>(&cs[512 + 8 * l]);
    const f32x4 c3 = *reinterpret_cast<const f32x4*>(&cs[512 + 8 * l + 4]);
    const int n0 = blockIdx.y * 64 + w * 16;
    const int nr = nrows[b];
    float acc[16];
    #pragma unroll
    for (int k = 0; k < 16; ++k) acc[k] = 0.f;
    const uint4* base = reinterpret_cast<const uint4*>(sc + ((size_t)b * Nn + n0) * Mn);
    uint4 a0 = base[l], d0 = base[64 + l], a1 = base[128 + l], d1 = base[192 + l];
    for (int j = 0; j < 16; j += 2) {
        uint4 na0 = {}, nd0 = {}, na1 = {}, nd1 = {};
        if (j < 14) {
            const uint4* nx = base + (size_t)(j + 2) * 128;
            na0 = nx[l]; nd0 = nx[64 + l]; na1 = nx[128 + l]; nd1 = nx[192 + l];
        }
        const float x0 = lo16(a0.x),  x1 = hi16(a0.x),  x2 = lo16(a0.y),  x3 = hi16(a0.y);
        const float x4 = lo16(a0.z),  x5 = hi16(a0.z),  x6 = lo16(a0.w),  x7 = hi16(a0.w);
        const float x8 = lo16(d0.x),  x9 = hi16(d0.x),  x10 = lo16(d0.y), x11 = hi16(d0.y);
        const float x12 = lo16(d0.z), x13 = hi16(d0.z), x14 = lo16(d0.w), x15 = hi16(d0.w);
        const float y0 = lo16(a1.x),  y1 = hi16(a1.x),  y2 = lo16(a1.y),  y3 = hi16(a1.y);
        const float y4 = lo16(a1.z),  y5 = hi16(a1.z),  y6 = lo16(a1.w),  y7 = hi16(a1.w);
        const float y8 = lo16(d1.x),  y9 = hi16(d1.x),  y10 = lo16(d1.y), y11 = hi16(d1.y);
        const float y12 = lo16(d1.z), y13 = hi16(d1.z), y14 = lo16(d1.w), y15 = hi16(d1.w);
        float part0 = x0 * c0.x + x1 * c0.y + x2 * c0.z + x3 * c0.w
                    + x4 * c1.x + x5 * c1.y + x6 * c1.z + x7 * c1.w
                    + x8 * c2.x + x9 * c2.y + x10 * c2.z + x11 * c2.w
                    + x12 * c3.x + x13 * c3.y + x14 * c3.z + x15 * c3.w;
        float part1 = y0 * c0.x + y1 * c0.y + y2 * c0.z + y3 * c0.w
                    + y4 * c1.x + y5 * c1.y + y6 * c1.z + y7 * c1.w
                    + y8 * c2.x + y9 * c2.y + y10 * c2.z + y11 * c2.w
                    + y12 * c3.x + y13 * c3.y + y14 * c3.z + y15 * c3.w;
        #pragma unroll
        for (int off = 1; off < 64; off <<= 1) {
            part0 += __shfl_xor(part0, off, 64);
            part1 += __shfl_xor(part1, off, 64);
        }
        const int n = n0 + j;
        const float rv0 = (n < nr && part0 > 0.f) ? 1.f / part0 : 0.f;
        const float rv1 = (n + 1 < nr && part1 > 0.f) ? 1.f / part1 : 0.f;
        acc[0]  += x0 * rv0 + y0 * rv1;   acc[1]  += x1 * rv0 + y1 * rv1;
        acc[2]  += x2 * rv0 + y2 * rv1;   acc[3]  += x3 * rv0 + y3 * rv1;
        acc[4]  += x4 * rv0 + y4 * rv1;   acc[5]  += x5 * rv0 + y5 * rv1;
        acc[6]  += x6 * rv0 + y6 * rv1;   acc[7]  += x7 * rv0 + y7 * rv1;
        acc[8]  += x8 * rv0 + y8 * rv1;   acc[9]  += x9 * rv0 + y9 * rv1;
        acc[10] += x10 * rv0 + y10 * rv1; acc[11] += x11 * rv0 + y11 * rv1;
        acc[12] += x12 * rv0 + y12 * rv1; acc[13] += x13 * rv0 + y13 * rv1;
        acc[14] += x14 * rv0 + y14 * rv1; acc[15] += x15 * rv0 + y15 * rv1;
        a0 = na0; d0 = nd0; a1 = na1; d1 = nd1;
    }
    red[w][2 * l]       = make_float4(acc[0], acc[1], acc[2], acc[3]);
    red[w][2 * l + 1]   = make_float4(acc[4], acc[5], acc[6], acc[7]);
    red[w][128 + 2 * l] = make_float4(acc[8], acc[9], acc[10], acc[11]);
    red[w][129 + 2 * l] = make_float4(acc[12], acc[13], acc[14], acc[15]);
    __syncthreads();
    const float4 r0 = red[0][t], r1 = red[1][t], r2 = red[2][t], r3 = red[3][t];
    float4 o = { r0.x + r1.x + r2.x + r3.x, r0.y + r1.y + r2.y + r3.y,
                 r0.z + r1.z + r2.z + r3.z, r0.w + r1.w + r2.w + r3.w };
    float* pp = pout + ((size_t)(b * SLOT) + blockIdx.y) * Mn;
    reinterpret_cast<float4*>(pp)[t] = o;
}

// ---- final pass: fold c, then read fp16 sc (L3-warm after sweep 4), compute
// last row factor in-wave, write f32 out (NT, write-once stream).
// Replaces the 256 MiB cold f32 re-read of s with a 128 MiB warm fp16 read.
__global__ __launch_bounds__(256) void final_kernel(
        const unsigned short* __restrict__ sc, const float* __restrict__ pin,
        const int* __restrict__ nrows, const int* __restrict__ ncols,
        float* __restrict__ out) {
    __shared__ float cs[1024];       // 4 KB
    const int b = blockIdx.x;
    const int t = threadIdx.x, w = t >> 6, l = t & 63;
    fold_c(pin, ncols, b, t, cs);
    __syncthreads();
    const f32x4 c0 = *reinterpret_cast<const f32x4*>(&cs[8 * l]);
    const f32x4 c1 = *reinterpret_cast<const f32x4*>(&cs[8 * l + 4]);
    const f32x4 c2 = *reinterpret_cast<const f32x4*>(&cs[512 + 8 * l]);
    const f32x4 c3 = *reinterpret_cast<const f32x4*>(&cs[512 + 8 * l + 4]);
    const int n0 = blockIdx.y * 64 + w * 16;
    const int nr = nrows[b];
    const uint4* base = reinterpret_cast<const uint4*>(sc + ((size_t)b * Nn + n0) * Mn);
    uint4 a0 = base[l], d0 = base[64 + l];
    for (int j = 0; j < 16; ++j) {
        uint4 na = {}, nd = {};
        if (j < 15) {
            const uint4* nx = base + (size_t)(j + 1) * 128;
            na = nx[l]; nd = nx[64 + l];
        }
        const float x0 = lo16(a0.x),  x1 = hi16(a0.x),  x2 = lo16(a0.y),  x3 = hi16(a0.y);
        const float x4 = lo16(a0.z),  x5 = hi16(a0.z),  x6 = lo16(a0.w),  x7 = hi16(a0.w);
        const float x8 = lo16(d0.x),  x9 = hi16(d0.x),  x10 = lo16(d0.y), x11 = hi16(d0.y);
        const float x12 = lo16(d0.z), x13 = hi16(d0.z), x14 = lo16(d0.w), x15 = hi16(d0.w);
        float part = x0 * c0.x + x1 * c0.y + x2 * c0.z + x3 * c0.w
                   + x4 * c1.x + x5 * c1.y + x6 * c1.z + x7 * c1.w
                   + x8 * c2.x + x9 * c2.y + x10 * c2.z + x11 * c2.w
                   + x12 * c3.x + x13 * c3.y + x14 * c3.z + x15 * c3.w;
        #pragma unroll
        for (int off = 1; off < 64; off <<= 1) part += __shfl_xor(part, off, 64);
        const int n = n0 + j;
        const float rv = (n < nr && part > 0.f) ? 1.f / part : 0.f;
        float* orow = out + ((size_t)b * Nn + n) * Mn;
        f32x4 o;
        o.x = x0 * c0.x * rv; o.y = x1 * c0.y * rv;
        o.z = x2 * c0.z * rv; o.w = x3 * c0.w * rv;
        __builtin_nontemporal_store(o, reinterpret_cast<f32x4*>(orow + 8 * l));
        o.x = x4 * c1.x * rv; o.y = x5 * c1.y * rv;
        o.z = x6 * c1.z * rv; o.w = x7 * c1.w * rv;
        __builtin_nontemporal_store(o, reinterpret_cast<f32x4*>(orow + 8 * l + 4));
        o.x = x8 * c2.x * rv;  o.y = x9 * c2.y * rv;
        o.z = x10 * c2.z * rv; o.w = x11 * c2.w * rv;
        __builtin_nontemporal_store(o, reinterpret_cast<f32x4*>(orow + 512 + 8 * l));
        o.x = x12 * c3.x * rv; o.y = x13 * c3.y * rv;
        o.z = x14 * c3.z * rv; o.w = x15 * c3.w * rv;
        __builtin_nontemporal_store(o, reinterpret_cast<f32x4*>(orow + 512 + 8 * l + 4));
        a0 = na; d0 = nd;
    }
}

extern "C" void kernel_launch(void* const* d_in, const int* in_sizes, int n_in,
                              void* d_out, int out_size, void* d_ws, size_t ws_size,
                              hipStream_t stream) {
    const float* s     = (const float*)d_in[0];
    const int*   nrows = (const int*)d_in[1];
    const int*   ncols = (const int*)d_in[2];
    float* out = (float*)d_out;

    // workspace: sc fp16 [B*N*M] (128 MiB) | pA [B*16*M] (4 MB) | pB (4 MB)
    unsigned short* sc = (unsigned short*)d_ws;
    float* pA = (float*)(sc + (size_t)Bn * Nn * Mn);
    float* pB = pA + (size_t)Bn * SLOT * Mn;

    // i=0: col-sum pass fused with fp16 compression (unmasked, r==1)
    fuse0_kernel<<<dim3(Bn, NSPLIT), 256, 0, stream>>>(s, sc, pA);
    // i=1..8: four fused (c-finalize + row-norm + col-sum) sweeps, ping-pong p
    rowcol_kernel<<<dim3(Bn, NSPLIT), 256, 0, stream>>>(sc, pA, nrows, ncols, pB);
    rowcol_kernel<<<dim3(Bn, NSPLIT), 256, 0, stream>>>(sc, pB, nrows, ncols, pA);
    rowcol_kernel<<<dim3(Bn, NSPLIT), 256, 0, stream>>>(sc, pA, nrows, ncols, pB);
    rowcol_kernel<<<dim3(Bn, NSPLIT), 256, 0, stream>>>(sc, pB, nrows, ncols, pA);
    // i=9: c-finalize + final row normalization from fp16 sc (saves 256 MiB
    // cold f32 re-read of s), f32 output write
    final_kernel<<<dim3(Bn, NSPLIT), 256, 0, stream>>>(sc, pA, nrows, ncols, out);
}